// Round 1
// baseline (591.560 us; speedup 1.0000x reference)
//
#include <hip/hip_runtime.h>

// VQ: B=16, C=D=256, H=64, W=64, K=1024
#define BB 16
#define CC 256
#define HH 64
#define WW 64
#define KK 1024
#define DD 256

// Kernel A: ehalf[k] = 0.5 * sum_d e[k][d]^2   (one wave per row)
__global__ __launch_bounds__(256) void vq_enorm_kernel(const float* __restrict__ e,
                                                       float* __restrict__ ehalf) {
    const int wave = threadIdx.x >> 6;
    const int lane = threadIdx.x & 63;
    const int k = blockIdx.x * 4 + wave;
    const float4 v = *reinterpret_cast<const float4*>(e + (size_t)k * DD + lane * 4);
    float s = v.x * v.x + v.y * v.y + v.z * v.z + v.w * v.w;
    #pragma unroll
    for (int off = 32; off; off >>= 1) s += __shfl_xor(s, off, 64);
    if (lane == 0) ehalf[k] = 0.5f * s;
}

// Kernel B: one block per (b,h): 64 tokens (w=0..63), all K codes.
// score_k = x.e_k - 0.5*||e_k||^2 ; argmax == argmin of squared distance.
__global__ __launch_bounds__(256) void vq_argmin_gather_kernel(
    const float* __restrict__ in, const float* __restrict__ emb,
    const float* __restrict__ ehalf, float* __restrict__ out) {

    __shared__ float x_lds[64][260];   // +4 pad: compute-phase b128 reads ~2-way (free)
    __shared__ float eh_lds[KK];
    __shared__ float red_v[64][16];
    __shared__ int   red_i[64][16];
    __shared__ int   idx_lds[64];

    const int tid = threadIdx.x;
    const int bid = blockIdx.x;
    const int b = bid >> 6, h = bid & 63;

    // ---- stage x tile (coalesced over w for each channel c) ----
    {
        const int w = tid & 63, cs = tid >> 6;
        const float* src = in + (size_t)b * CC * HH * WW + (size_t)h * WW + w;
        for (int c = cs; c < CC; c += 4)
            x_lds[w][c] = src[(size_t)c * (HH * WW)];
        for (int k = tid; k < KK; k += 256)
            eh_lds[k] = ehalf[k];
    }
    __syncthreads();

    // ---- 16x16 thread tile: thread (i,j) -> tokens {i+16t}, codes {c0..c0+3} ----
    const int i = tid & 15;
    const int j = tid >> 4;

    float best_v[4];
    int   best_i[4];
    #pragma unroll
    for (int t = 0; t < 4; ++t) { best_v[t] = -1e30f; best_i[t] = 0; }

    for (int chunk = 0; chunk < KK; chunk += 64) {
        const int c0 = chunk + j * 4;
        float acc[4][4];
        #pragma unroll
        for (int cj = 0; cj < 4; ++cj) {
            const float nh = -eh_lds[c0 + cj];
            #pragma unroll
            for (int t = 0; t < 4; ++t) acc[t][cj] = nh;
        }
        const float* e0 = emb + (size_t)c0 * DD;
        #pragma unroll 2
        for (int d = 0; d < DD; d += 4) {
            float4 xv[4], ev[4];
            #pragma unroll
            for (int t = 0; t < 4; ++t)
                xv[t] = *reinterpret_cast<const float4*>(&x_lds[i + 16 * t][d]);
            #pragma unroll
            for (int cj = 0; cj < 4; ++cj)
                ev[cj] = *reinterpret_cast<const float4*>(e0 + (size_t)cj * DD + d);
            #pragma unroll
            for (int t = 0; t < 4; ++t) {
                #pragma unroll
                for (int cj = 0; cj < 4; ++cj) {
                    acc[t][cj] += xv[t].x * ev[cj].x + xv[t].y * ev[cj].y
                                + xv[t].z * ev[cj].z + xv[t].w * ev[cj].w;
                }
            }
        }
        // running argmax; codes ascend within thread -> strict > keeps lowest idx
        #pragma unroll
        for (int cj = 0; cj < 4; ++cj) {
            #pragma unroll
            for (int t = 0; t < 4; ++t) {
                if (acc[t][cj] > best_v[t]) { best_v[t] = acc[t][cj]; best_i[t] = c0 + cj; }
            }
        }
    }

    // ---- reduce across the 16 j-groups per token (tie -> lower index) ----
    #pragma unroll
    for (int t = 0; t < 4; ++t) {
        red_v[i + 16 * t][j] = best_v[t];
        red_i[i + 16 * t][j] = best_i[t];
    }
    __syncthreads();
    if (tid < 64) {
        float bv = red_v[tid][0]; int bi = red_i[tid][0];
        #pragma unroll
        for (int jj = 1; jj < 16; ++jj) {
            const float v = red_v[tid][jj]; const int id = red_i[tid][jj];
            if (v > bv || (v == bv && id < bi)) { bv = v; bi = id; }
        }
        idx_lds[tid] = bi;
    }
    __syncthreads();

    // ---- gather + straight-through write (out = x + (q - x), same rounding as ref) ----
    {
        const int w = tid & 63, cs = tid >> 6;
        float* dst = out + (size_t)b * CC * HH * WW + (size_t)h * WW + w;
        const float* erow = emb + (size_t)idx_lds[w] * DD;
        for (int c = cs; c < CC; c += 4) {
            const float x = x_lds[w][c];
            const float q = erow[c];
            dst[(size_t)c * (HH * WW)] = x + (q - x);
        }
    }
}

extern "C" void kernel_launch(void* const* d_in, const int* in_sizes, int n_in,
                              void* d_out, int out_size, void* d_ws, size_t ws_size,
                              hipStream_t stream) {
    const float* in  = (const float*)d_in[0];
    const float* emb = (const float*)d_in[1];
    float* out   = (float*)d_out;
    float* ehalf = (float*)d_ws;   // 1024 floats = 4 KiB

    vq_enorm_kernel<<<KK / 4, 256, 0, stream>>>(emb, ehalf);
    vq_argmin_gather_kernel<<<BB * HH, 256, 0, stream>>>(in, emb, ehalf, out);
}

// Round 5
// 562.670 us; speedup vs baseline: 1.0513x; 1.0513x over previous
//
#include <hip/hip_runtime.h>

// VQ: B=16, C=D=256, H=64, W=64, K=1024
#define BB 16
#define CC 256
#define HH 64
#define WW 64
#define KK 1024
#define DD 256

// Kernel A: ehalf[k] = 0.5 * sum_d e[k][d]^2   (one wave per row)
__global__ __launch_bounds__(256) void vq_enorm_kernel(const float* __restrict__ e,
                                                       float* __restrict__ ehalf) {
    const int wave = threadIdx.x >> 6;
    const int lane = threadIdx.x & 63;
    const int k = blockIdx.x * 4 + wave;
    const float4 v = *reinterpret_cast<const float4*>(e + (size_t)k * DD + lane * 4);
    float s = v.x * v.x + v.y * v.y + v.z * v.z + v.w * v.w;
    #pragma unroll
    for (int off = 32; off; off >>= 1) s += __shfl_xor(s, off, 64);
    if (lane == 0) ehalf[k] = 0.5f * s;
}

// Kernel B: one block per (b,h): 64 tokens (w=0..63), all K codes.
// score_k = x.e_k - 0.5*||e_k||^2 ; argmax == argmin of squared distance.
// Thread tile: 4 tokens x 8 codes = 32 accs; inner loop = pure fmaf chains.
__global__ __launch_bounds__(256) void vq_argmin_gather_kernel(
    const float* __restrict__ in, const float* __restrict__ emb,
    const float* __restrict__ ehalf, float* __restrict__ out) {

    __shared__ float x_lds[64][260];   // stride 260: row->bank offset 4, 2-way alias = free
    __shared__ float red_v[64][16];
    __shared__ int   red_i[64][16];
    __shared__ int   idx_lds[64];

    const int tid = threadIdx.x;
    const int bid = blockIdx.x;
    const int b = bid >> 6, h = bid & 63;
    const int w = tid & 63, cs = tid >> 6;

    // ---- stage x tile (coalesced over w for each channel c) ----
    {
        const float* src = in + (size_t)b * CC * HH * WW + (size_t)h * WW + w;
        #pragma unroll
        for (int c = cs; c < CC; c += 4)
            x_lds[w][c] = src[(size_t)c * (HH * WW)];
    }
    __syncthreads();

    // ---- thread tile: (i,j): tokens {i+16t, t=0..3}, codes {c0..c0+7} ----
    const int i = tid & 15;
    const int j = tid >> 4;

    float best_v[4];
    int   best_i[4];
    #pragma unroll
    for (int t = 0; t < 4; ++t) { best_v[t] = -3.4e38f; best_i[t] = 0; }

    for (int chunk = 0; chunk < KK; chunk += 128) {
        const int c0 = chunk + j * 8;
        const float* e0 = emb + (size_t)c0 * DD;

        float acc[4][8];
        #pragma unroll
        for (int cj = 0; cj < 8; ++cj) {
            const float nh = -ehalf[c0 + cj];
            #pragma unroll
            for (int t = 0; t < 4; ++t) acc[t][cj] = nh;
        }

        #pragma unroll 2
        for (int d = 0; d < DD; d += 4) {
            float4 xv[4], ev[8];
            #pragma unroll
            for (int t = 0; t < 4; ++t)
                xv[t] = *reinterpret_cast<const float4*>(&x_lds[i + 16 * t][d]);
            #pragma unroll
            for (int cj = 0; cj < 8; ++cj)
                ev[cj] = *reinterpret_cast<const float4*>(e0 + (size_t)cj * DD + d);
            #pragma unroll
            for (int t = 0; t < 4; ++t) {
                #pragma unroll
                for (int cj = 0; cj < 8; ++cj) {
                    float a = acc[t][cj];
                    a = fmaf(xv[t].x, ev[cj].x, a);
                    a = fmaf(xv[t].y, ev[cj].y, a);
                    a = fmaf(xv[t].z, ev[cj].z, a);
                    a = fmaf(xv[t].w, ev[cj].w, a);
                    acc[t][cj] = a;
                }
            }
        }

        // running argmax; code ids ascend within thread -> strict > keeps lowest idx
        #pragma unroll
        for (int cj = 0; cj < 8; ++cj) {
            #pragma unroll
            for (int t = 0; t < 4; ++t) {
                if (acc[t][cj] > best_v[t]) { best_v[t] = acc[t][cj]; best_i[t] = c0 + cj; }
            }
        }
    }

    // ---- reduce across the 16 j-groups per token (tie -> lower index) ----
    #pragma unroll
    for (int t = 0; t < 4; ++t) {
        red_v[i + 16 * t][j] = best_v[t];
        red_i[i + 16 * t][j] = best_i[t];
    }
    __syncthreads();
    if (tid < 64) {
        float bv = red_v[tid][0]; int bi = red_i[tid][0];
        #pragma unroll
        for (int jj = 1; jj < 16; ++jj) {
            const float v = red_v[tid][jj]; const int id = red_i[tid][jj];
            if (v > bv || (v == bv && id < bi)) { bv = v; bi = id; }
        }
        idx_lds[tid] = bi;
    }
    __syncthreads();

    // ---- gather + straight-through write (out = x + (q - x), ref rounding) ----
    {
        float* dst = out + (size_t)b * CC * HH * WW + (size_t)h * WW + w;
        const float* erow = emb + (size_t)idx_lds[w] * DD;
        #pragma unroll
        for (int c = cs; c < CC; c += 4) {
            const float x = x_lds[w][c];
            const float q = erow[c];
            dst[(size_t)c * (HH * WW)] = x + (q - x);
        }
    }
}

extern "C" void kernel_launch(void* const* d_in, const int* in_sizes, int n_in,
                              void* d_out, int out_size, void* d_ws, size_t ws_size,
                              hipStream_t stream) {
    const float* in  = (const float*)d_in[0];
    const float* emb = (const float*)d_in[1];
    float* out   = (float*)d_out;
    float* ehalf = (float*)d_ws;   // 1024 floats = 4 KiB

    vq_enorm_kernel<<<KK / 4, 256, 0, stream>>>(emb, ehalf);
    vq_argmin_gather_kernel<<<BB * HH, 256, 0, stream>>>(in, emb, ehalf, out);
}